// Round 3
// baseline (173.054 us; speedup 1.0000x reference)
//
#include <hip/hip_runtime.h>

#define TEMP    0.5f
#define LOG2E   1.4426950408889634f
#define C2      (LOG2E / TEMP)        /* t = dot * C2 */
#define MSHIFT  160.0f                /* fixed base-2 softmax shift */
#define LN2     0.6931471805599453f
#define NROWS   16384
#define BHALF   8192
#define DDIM    128
#define PREPB   2048                  /* k_prep blocks = 524288/256 */
#define MAINB   512                   /* k_main grid */

typedef __bf16 bf16x8 __attribute__((ext_vector_type(8)));
typedef float  f32x16 __attribute__((ext_vector_type(16)));

__device__ __forceinline__ float fexp2(float x) {
#if __has_builtin(__builtin_amdgcn_exp2f)
  return __builtin_amdgcn_exp2f(x);
#else
  return exp2f(x);
#endif
}

__device__ __forceinline__ unsigned short f2bf(float f) {
  unsigned int u = __float_as_uint(f);
  unsigned int r = (u + 0x7FFFu + ((u >> 16) & 1u)) >> 16;  // RNE
  return (unsigned short)r;
}

// ---------------------------------------------------------------------------
// zbF frag-major layout: row r, k-index k:
//   g = r/32, lo = r%32, khi = k/8, j = k%8
//   short index = g*4096 + khi*256 + lo*8 + j
// A wave's frag load (fixed khi): 64 lanes read a contiguous 1KB block.
// ---------------------------------------------------------------------------

// k_prep: cast concat(z_i,z_j) fp32->bf16 into frag-major zbF; per-block
// partial dot(z_i,z_j) -> Pp[block]; zero S and the completion counter.
__global__ void k_prep(const float* __restrict__ zi, const float* __restrict__ zj,
                       unsigned short* __restrict__ zbF,
                       float* __restrict__ S, float* __restrict__ Pp,
                       unsigned int* __restrict__ Cnt) {
  const int t   = blockIdx.x * 256 + threadIdx.x;   // 0..524287 float4 groups
  const int row = t >> 5;                           // 32 float4 per 128-elt row
  const int k0  = (t & 31) * 4;
  const float* src = (row < BHALF) ? (zi + (size_t)row * DDIM)
                                   : (zj + (size_t)(row - BHALF) * DDIM);
  float4 v = *reinterpret_cast<const float4*>(src + k0);

  const int g = row >> 5, lo = row & 31, khi = k0 >> 3, j0 = k0 & 7;
  ushort4 o;
  o.x = f2bf(v.x); o.y = f2bf(v.y); o.z = f2bf(v.z); o.w = f2bf(v.w);
  *reinterpret_cast<ushort4*>(zbF + (size_t)g * 4096 + khi * 256 + lo * 8 + j0) = o;

  float dot = 0.f;
  if (row < BHALF) {
    float4 w = *reinterpret_cast<const float4*>(zj + (size_t)row * DDIM + k0);
    dot = fmaf(v.x, w.x, fmaf(v.y, w.y, fmaf(v.z, w.z, v.w * w.w)));
  }
#pragma unroll
  for (int m = 32; m >= 1; m >>= 1) dot += __shfl_xor(dot, m, 64);
  __shared__ float red[4];
  if ((threadIdx.x & 63) == 0) red[threadIdx.x >> 6] = dot;
  __syncthreads();
  if (threadIdx.x == 0) Pp[blockIdx.x] = red[0] + red[1] + red[2] + red[3];

  if (t < NROWS) S[t] = 0.f;
  if (t == 0)    *Cnt = 0u;
}

// ---------------------------------------------------------------------------
// k_main: 128 persistent rows/wave as MFMA B operand; streams 32-col tiles as
// A. Phase-pipelined: exp of phase p-1 overlaps MFMA chains of phase p
// (ping-pong accE/accO, no register copies). Last block finalizes the loss.
// ---------------------------------------------------------------------------
__device__ __forceinline__ void loadA(bf16x8 (&a)[8], const unsigned short* ap) {
#pragma unroll
  for (int ks = 0; ks < 8; ++ks)
    a[ks] = *reinterpret_cast<const bf16x8*>(ap + ks * 512);
}

__device__ __forceinline__ void mfmaPhase(const bf16x8 (&a)[8], const bf16x8 (&b0)[8],
                                          const bf16x8 (&b1)[8], const f32x16& z,
                                          f32x16& o0, f32x16& o1) {
  o0 = __builtin_amdgcn_mfma_f32_32x32x16_bf16(a[0], b0[0], z, 0, 0, 0);
  o1 = __builtin_amdgcn_mfma_f32_32x32x16_bf16(a[0], b1[0], z, 0, 0, 0);
#pragma unroll
  for (int ks = 1; ks < 8; ++ks) {
    o0 = __builtin_amdgcn_mfma_f32_32x32x16_bf16(a[ks], b0[ks], o0, 0, 0, 0);
    o1 = __builtin_amdgcn_mfma_f32_32x32x16_bf16(a[ks], b1[ks], o1, 0, 0, 0);
  }
}

template <bool MK>
__device__ __forceinline__ void expPair(const f32x16& A, const f32x16& B,
                                        float (&sA)[2], float (&sB)[2],
                                        int dA, int dB, int hi) {
#pragma unroll
  for (int r = 0; r < 16; ++r) {
    float eA = fexp2(fmaf(A[r], C2, -MSHIFT));
    float eB = fexp2(fmaf(B[r], C2, -MSHIFT));
    if (MK) {
      const int rloc = (r & 3) + 8 * (r >> 2) + 4 * hi;  // C/D reg map (verified)
      if (rloc == dA) eA = 0.f;
      if (rloc == dB) eB = 0.f;
    }
    if (r & 1) { sA[1] += eA; sB[1] += eB; }
    else       { sA[0] += eA; sB[0] += eB; }
  }
}

__global__ __launch_bounds__(256, 2)
void k_main(const unsigned short* __restrict__ zbF, float* __restrict__ S,
            const float* __restrict__ Pp, unsigned int* __restrict__ Cnt,
            float* __restrict__ out) {
  const int wave = threadIdx.x >> 6;
  const int lane = threadIdx.x & 63;
  const int lo = lane & 31;
  const int hi = lane >> 5;
  const int rb = blockIdx.x & 31;       // 32 row blocks of 512 rows
  const int cc = blockIdx.x >> 5;       // 16 col chunks of 1024 cols
  const int row0w = rb * 512 + wave * 128;

  // persistent row frags (B operand): 4 row-tiles x 8 k-steps = 128 regs
  bf16x8 b[4][8];
#pragma unroll
  for (int rt = 0; rt < 4; ++rt) {
    const unsigned short* bp = zbF + (size_t)((row0w >> 5) + rt) * 4096 + hi * 256 + lo * 8;
    loadA(b[rt], bp);
  }

  const f32x16 kZ = {};
  float s[4][2];
#pragma unroll
  for (int rt = 0; rt < 4; ++rt) { s[rt][0] = 0.f; s[rt][1] = 0.f; }

  const int c0base = cc * 1024;
  const unsigned short* abase = zbF + (size_t)(c0base >> 5) * 4096 + hi * 256 + lo * 8;

  bf16x8 a[8];
  loadA(a, abase);

  f32x16 accE0, accE1, accO0, accO1;

  // phase 0: tile 0, row-tiles 0,1
  mfmaPhase(a, b[0], b[1], kZ, accE0, accE1);

  for (int it = 0; it < 32; ++it) {
    const int dr = c0base + it * 32 - row0w;
    const bool dg = (unsigned)dr < 128u;
    const int rtd = dg ? (dr >> 5) : -1;

    // phase 2it+1: tile it, row-tiles 2,3
    mfmaPhase(a, b[2], b[3], kZ, accO0, accO1);
    if (it + 1 < 32)
      loadA(a, abase + (size_t)(it + 1) * 4096);  // a free; consumed ~400 cyc later

    // exp phase 2it (tile it, rt 0,1) under accO's MFMA shadow
    if (dg && rtd <= 1)
      expPair<true >(accE0, accE1, s[0], s[1], rtd == 0 ? lo : -1, rtd == 1 ? lo : -1, hi);
    else
      expPair<false>(accE0, accE1, s[0], s[1], -1, -1, hi);

    // phase 2it+2: tile it+1, row-tiles 0,1
    if (it + 1 < 32)
      mfmaPhase(a, b[0], b[1], kZ, accE0, accE1);

    // exp phase 2it+1 (tile it, rt 2,3) under accE's MFMA shadow
    if (dg && rtd >= 2)
      expPair<true >(accO0, accO1, s[2], s[3], rtd == 2 ? lo : -1, rtd == 3 ? lo : -1, hi);
    else
      expPair<false>(accO0, accO1, s[2], s[3], -1, -1, hi);
  }

  // row sums: fold hi halves, one atomic per row per col-chunk
#pragma unroll
  for (int rt = 0; rt < 4; ++rt) {
    float v = s[rt][0] + s[rt][1];
    v += __shfl_xor(v, 32, 64);
    if (hi == 0) atomicAdd(&S[row0w + rt * 32 + lo], v);
  }

  // ---- fused finalize: last block computes the loss ----
  __threadfence();
  __shared__ bool isLast;
  if (threadIdx.x == 0)
    isLast = (atomicAdd(Cnt, 1u) == MAINB - 1);
  __syncthreads();
  if (!isLast) return;
  __threadfence();

  const int t = threadIdx.x;
  float q = 0.f;
  for (int r = t; r < NROWS; r += 256) {
    float sv = __hip_atomic_load(&S[r], __ATOMIC_RELAXED, __HIP_MEMORY_SCOPE_AGENT);
    q += LN2 * (MSHIFT + __log2f(sv));
  }
  for (int r = t; r < PREPB; r += 256)
    q -= 4.0f * Pp[r];
  __shared__ float red[256];
  red[t] = q;
  __syncthreads();
  for (int s2 = 128; s2 > 0; s2 >>= 1) {
    if (t < s2) red[t] += red[t + s2];
    __syncthreads();
  }
  if (t == 0) out[0] = red[0] / (float)NROWS;
}

// ---------------------------------------------------------------------------
extern "C" void kernel_launch(void* const* d_in, const int* in_sizes, int n_in,
                              void* d_out, int out_size, void* d_ws, size_t ws_size,
                              hipStream_t stream) {
  const float* zi = (const float*)d_in[0];
  const float* zj = (const float*)d_in[1];
  unsigned short* zbF = (unsigned short*)d_ws;                     // 4 MB
  float* S  = (float*)((char*)d_ws + (size_t)NROWS * DDIM * 2);    // 64 KB
  float* Pp = S + NROWS;                                           // 8 KB
  unsigned int* Cnt = (unsigned int*)(Pp + PREPB);                 // 4 B
  float* out = (float*)d_out;

  hipLaunchKernelGGL(k_prep, dim3(PREPB), dim3(256), 0, stream, zi, zj, zbF, S, Pp, Cnt);
  hipLaunchKernelGGL(k_main, dim3(MAINB), dim3(256), 0, stream, zbF, S, Pp, Cnt, out);
}